// Round 16
// baseline (96.505 us; speedup 1.0000x reference)
//
#include <hip/hip_runtime.h>
#include <hip/hip_fp16.h>
#include <math.h>

#define HEADS 8
#define DIM 32
#define NEG_SLOPE 0.2f

typedef float f32x4 __attribute__((ext_vector_type(4)));

__device__ inline float2 u2f2(unsigned int u) {
    __half2 h = __builtin_bit_cast(__half2, u);
    return __half22float2(h);
}
__device__ inline unsigned short f2bf(float f) {       // RNE f32 -> bf16
    unsigned int u = __builtin_bit_cast(unsigned int, f);
    u += 0x7FFFu + ((u >> 16) & 1u);
    return (unsigned short)(u >> 16);
}
__device__ inline float bf2f(unsigned short b) {
    unsigned int u = ((unsigned int)b) << 16;
    return __builtin_bit_cast(float, u);
}

// Prep: one wave per node — logits el/er in [node][8] layout and fp16 feat
// node-major feat_h[node][256] (512B rows, coalesced uint2/lane).
__global__ __launch_bounds__(256) void gat_prep_kernel(
    const float4* __restrict__ feat4,    // node row = 64 float4
    const float4* __restrict__ attn_l4,  // 64 float4 (8 heads x 8)
    const float4* __restrict__ attn_r4,
    float* __restrict__ el_n,            // [n_nodes][8]
    float* __restrict__ er_n,            // [n_nodes][8]
    uint2* __restrict__ feat_h2,         // [n_nodes][64] uint2 (fp16)
    int n_nodes) {
    int wid = (blockIdx.x * blockDim.x + threadIdx.x) >> 6;
    if (wid >= n_nodes) return;
    int lane = threadIdx.x & 63;
    int h = lane >> 3;
    int q = lane & 7;

    float4 al = attn_l4[lane];
    float4 ar = attn_r4[lane];
    float4 v  = feat4[(size_t)wid * 64 + lane];

    float sl = v.x * al.x + v.y * al.y + v.z * al.z + v.w * al.w;
    float sr = v.x * ar.x + v.y * ar.y + v.z * ar.z + v.w * ar.w;
#pragma unroll
    for (int off = 1; off < 8; off <<= 1) {
        sl += __shfl_xor(sl, off, 64);
        sr += __shfl_xor(sr, off, 64);
    }
    if (q == 0) {
        el_n[(unsigned)wid * 8 + h] = sl;
        er_n[(unsigned)wid * 8 + h] = sr;
    }
    uint2 o;
    o.x = __builtin_bit_cast(unsigned int, __floats2half2_rn(v.x, v.y));
    o.y = __builtin_bit_cast(unsigned int, __floats2half2_rn(v.z, v.w));
    feat_h2[(size_t)wid * 64 + lane] = o;
}

// Edge-parallel: one thread per edge. (a) CSR rowptr build from sorted dst.
// (b) w_e[e][0..7] = bf16(exp(lrelu(el[u][h]+er[v][h]))) packed 16B store.
__global__ __launch_bounds__(256) void gat_edgew_kernel(
    const float4* __restrict__ el_n4,    // [n_nodes][2] float4
    const float4* __restrict__ er_n4,
    const int* __restrict__ src_idx,
    const int* __restrict__ dst_idx,
    int* __restrict__ rowptr,
    uint4* __restrict__ w_e4,            // [n_edges] x 16B (8 bf16)
    int n_edges, int n_nodes) {
    int e = blockIdx.x * blockDim.x + threadIdx.x;
    if (e >= n_edges) return;
    int d = dst_idx[e];
    int prev = (e > 0) ? dst_idx[e - 1] : -1;
    for (int v = prev + 1; v <= d; ++v) rowptr[v] = e;
    if (e == n_edges - 1) {
        for (int v = d + 1; v <= n_nodes; ++v) rowptr[v] = n_edges;
    }

    unsigned u = (unsigned)src_idx[e];
    float4 elA = el_n4[u * 2], elB = el_n4[u * 2 + 1];
    float4 erA = er_n4[(unsigned)d * 2], erB = er_n4[(unsigned)d * 2 + 1];
    float s[8];
    s[0] = elA.x + erA.x; s[1] = elA.y + erA.y;
    s[2] = elA.z + erA.z; s[3] = elA.w + erA.w;
    s[4] = elB.x + erB.x; s[5] = elB.y + erB.y;
    s[6] = elB.z + erB.z; s[7] = elB.w + erB.w;
    unsigned short wb[8];
#pragma unroll
    for (int h = 0; h < 8; ++h) {
        float t = fmaxf(s[h], NEG_SLOPE * s[h]);   // leaky relu
        wb[h] = f2bf(__expf(t));
    }
    uint4 pk;
    pk.x = (unsigned)wb[0] | ((unsigned)wb[1] << 16);
    pk.y = (unsigned)wb[2] | ((unsigned)wb[3] << 16);
    pk.z = (unsigned)wb[4] | ((unsigned)wb[5] << 16);
    pk.w = (unsigned)wb[6] | ((unsigned)wb[7] << 16);
    w_e4[e] = pk;
}

// Aggregate: one wave per node; lane = (h = lane>>3, d4 = lane&7).
// UNROLL-16: with avg degree 16 most segments complete in ONE batch;
// 16 feat + 16 w loads in flight per lane. Uniform src s_loads, inline den,
// clamp + w=0 tail predication, single divide in epilogue.
__global__ __launch_bounds__(256) void gat_aggregate_kernel(
    const uint2* __restrict__ feat_h,         // [n_nodes][64] uint2
    const unsigned short* __restrict__ w_e,   // [n_edges][8] bf16
    const int* __restrict__ src_idx,
    const int* __restrict__ rowptr,
    f32x4* __restrict__ out4,                 // [n_nodes][64] float4-units
    int n_nodes) {
    int vraw = (blockIdx.x * blockDim.x + threadIdx.x) >> 6;
    if (vraw >= n_nodes) return;
    int v = __builtin_amdgcn_readfirstlane(vraw);
    int lane = threadIdx.x & 63;
    int h = lane >> 3;

    int start = __builtin_amdgcn_readfirstlane(rowptr[v]);
    int end   = __builtin_amdgcn_readfirstlane(rowptr[v + 1]);

    unsigned obase = ((unsigned)v << 6) + (unsigned)lane;
    if (start == end) {
        f32x4 z = {0.f, 0.f, 0.f, 0.f};
        __builtin_nontemporal_store(z, &out4[obase]);
        return;
    }
    int endm1 = end - 1;

    float denA = 0.f, denB = 0.f;
    f32x4 acc0 = {0.f, 0.f, 0.f, 0.f};
    f32x4 acc1 = {0.f, 0.f, 0.f, 0.f};

    for (int e = start; e < end; e += 16) {
        int   idx[16];
        uint2 fr[16];
        float wv[16];
#pragma unroll
        for (int i = 0; i < 16; ++i) {
            int ee = (e + i < endm1) ? (e + i) : endm1;   // scalar clamp
            idx[i] = src_idx[ee];                          // uniform -> s_load
            wv[i]  = bf2f(w_e[(size_t)ee * 8 + h]);
            if (e + i > endm1) wv[i] = 0.f;
        }
#pragma unroll
        for (int i = 0; i < 16; ++i) {
            fr[i] = feat_h[((unsigned)idx[i] << 6) + (unsigned)lane];
        }
#pragma unroll
        for (int i = 0; i < 16; ++i) {
            float w = wv[i];
            float2 lo = u2f2(fr[i].x);
            float2 hi = u2f2(fr[i].y);
            if (i & 1) {
                denB += w;
                acc1.x += w * lo.x; acc1.y += w * lo.y;
                acc1.z += w * hi.x; acc1.w += w * hi.y;
            } else {
                denA += w;
                acc0.x += w * lo.x; acc0.y += w * lo.y;
                acc0.z += w * hi.x; acc0.w += w * hi.y;
            }
        }
    }
    float invd = 1.f / (denA + denB);
    f32x4 r = acc0 + acc1;
    r.x *= invd; r.y *= invd; r.z *= invd; r.w *= invd;
    __builtin_nontemporal_store(r, &out4[obase]);
}

extern "C" void kernel_launch(void* const* d_in, const int* in_sizes, int n_in,
                              void* d_out, int out_size, void* d_ws, size_t ws_size,
                              hipStream_t stream) {
    const float* feat   = (const float*)d_in[0];
    const float* attn_l = (const float*)d_in[1];
    const float* attn_r = (const float*)d_in[2];
    const int*   src    = (const int*)d_in[3];
    const int*   dst    = (const int*)d_in[4];
    float* out = (float*)d_out;

    int n_edges = in_sizes[3];
    int n_nodes = out_size / (HEADS * DIM);
    int nh = n_nodes * HEADS;

    // Workspace: el_n[8N] f32 | er_n[8N] f32 | rowptr[N+1] | (align16)
    //            | feat_h [N][256] fp16 = nh*64 B | w_e[E][8] bf16 = E*16 B
    char* ws = (char*)d_ws;
    float* el_n = (float*)ws;                     ws += (size_t)nh * 4;
    float* er_n = (float*)ws;                     ws += (size_t)nh * 4;
    int* rowptr = (int*)ws;                       ws += (size_t)(n_nodes + 1) * 4;
    ws = (char*)(((uintptr_t)ws + 15) & ~(uintptr_t)15);
    uint2* feat_h2 = (uint2*)ws;                  ws += (size_t)nh * 64;
    unsigned short* w_e = (unsigned short*)ws;

    hipLaunchKernelGGL(gat_prep_kernel,
                       dim3((n_nodes + 3) / 4), dim3(256), 0, stream,
                       (const float4*)feat, (const float4*)attn_l,
                       (const float4*)attn_r, el_n, er_n, feat_h2, n_nodes);

    hipLaunchKernelGGL(gat_edgew_kernel,
                       dim3((n_edges + 255) / 256), dim3(256), 0, stream,
                       (const float4*)el_n, (const float4*)er_n, src, dst,
                       rowptr, (uint4*)w_e, n_edges, n_nodes);

    hipLaunchKernelGGL(gat_aggregate_kernel,
                       dim3((n_nodes + 3) / 4), dim3(256), 0, stream,
                       feat_h2, w_e, src, rowptr, (f32x4*)out, n_nodes);
}